// Round 3
// baseline (78177.228 us; speedup 1.0000x reference)
//
#include <hip/hip_runtime.h>
#include <stdint.h>

typedef unsigned short u16;

#define BB    16
#define TENC  256
#define TDEC  200
#define NMELS 80
#define EDIM  512
#define PREN  256
#define ARN   1024
#define ATTN  128
#define NFILT 32
#define KSIZE 31

#define MASK_PARTITIONABLE 1

__host__ __device__ inline void tf2x32(uint32_t k0, uint32_t k1, uint32_t x0, uint32_t x1,
                                       uint32_t &y0, uint32_t &y1) {
  uint32_t ks2 = k0 ^ k1 ^ 0x1BD11BDAu;
  x0 += k0; x1 += k1;
  const int R0[4] = {13, 15, 26, 6};
  const int R1[4] = {17, 29, 16, 24};
#pragma unroll
  for (int g = 0; g < 5; ++g) {
    const int *R = (g & 1) ? R1 : R0;
#pragma unroll
    for (int i = 0; i < 4; ++i) {
      x0 += x1;
      x1 = (x1 << R[i]) | (x1 >> (32 - R[i]));
      x1 ^= x0;
    }
    switch (g) {
      case 0: x0 += k1;  x1 += ks2 + 1u; break;
      case 1: x0 += ks2; x1 += k0 + 2u;  break;
      case 2: x0 += k0;  x1 += k1 + 3u;  break;
      case 3: x0 += k1;  x1 += ks2 + 4u; break;
      case 4: x0 += ks2; x1 += k0 + 5u;  break;
    }
  }
  y0 = x0; y1 = x1;
}

__device__ inline bool keep_mask(uint32_t k0, uint32_t k1, uint32_t idx) {
#if MASK_PARTITIONABLE
  uint32_t y0, y1;
  tf2x32(k0, k1, 0u, idx, y0, y1);
  return (((y0 ^ y1) >> 31) == 0u);
#else
  const uint32_t half = (201u * 16u * 256u) / 2u;
  uint32_t y0, y1;
  if (idx < half) { tf2x32(k0, k1, idx, idx + half, y0, y1); return ((y0 >> 31) == 0u); }
  else            { tf2x32(k0, k1, idx - half, idx, y0, y1); return ((y1 >> 31) == 0u); }
#endif
}

__device__ inline float bf2f(u16 v) {
  union { uint32_t u; float f; } x;
  x.u = ((uint32_t)v) << 16;
  return x.f;
}
__device__ inline u16 f2bf(float f) {
  union { float f; uint32_t u; } x;
  x.f = f;
  uint32_t r = ((x.u >> 16) & 1u) + 0x7FFFu;
  return (u16)((x.u + r) >> 16);
}
__device__ inline float sigm(float x) { return 1.f / (1.f + expf(-x)); }

// flag F: 1 => buffers are float32, 0 => bf16
__device__ inline float ldin(const void *p, size_t i, int F) {
  return F ? ((const float *)p)[i] : bf2f(((const u16 *)p)[i]);
}
__device__ inline void stf(void *p, size_t i, float v, int F) {
  if (F) ((float *)p)[i] = v;
  else   ((u16 *)p)[i] = f2bf(v);
}

// ---------------- dtype probe ----------------
__global__ void k_detect(const void *mem, int *flag) {
  if (threadIdx.x == 0 && blockIdx.x == 0) {
    const u16 *p = (const u16 *)mem;
    int bad = 0;
    for (int i = 0; i < 2048; ++i) {
      uint32_t e = (p[i] >> 7) & 0xFFu;  // bf16 exponent field
      if (e >= 134u) bad++;              // |v| >= 128: impossible for bf16 N(0,1)
    }
    *flag = (bad > 16) ? 1 : 0;
  }
}

// ---------------- prenet layer 1 ----------------
__global__ __launch_bounds__(256) void k_prenet1(const void *__restrict__ dec_in,
                                                 const void *__restrict__ W1,
                                                 u16 *__restrict__ x1,
                                                 uint32_t k0, uint32_t k1,
                                                 const int *__restrict__ dflag) {
  const int F = *dflag;
  int bid = blockIdx.x;
  int t = bid >> 4, b = bid & 15;
  int tid = threadIdx.x;
  __shared__ float di[NMELS];
  if (tid < NMELS)
    di[tid] = (t == 0) ? 0.f : ldin(dec_in, ((size_t)b * NMELS + tid) * TDEC + (t - 1), F);
  __syncthreads();
  int j = tid;
  float acc = 0.f;
  for (int m = 0; m < NMELS; ++m) acc += di[m] * ldin(W1, (size_t)m * PREN + j, F);
  acc = fmaxf(acc, 0.f);
  uint32_t idx = ((uint32_t)(t * BB + b)) * PREN + (uint32_t)j;
  acc = keep_mask(k0, k1, idx) ? acc * 2.f : 0.f;
  x1[(t * BB + b) * PREN + j] = f2bf(acc);
}

// ---------------- prenet layer 2 -> preT (f32, transposed [t][j][b]) ----------------
__global__ __launch_bounds__(256) void k_prenet2(const u16 *__restrict__ x1,
                                                 const void *__restrict__ W2,
                                                 float *__restrict__ preT,
                                                 uint32_t k0, uint32_t k1,
                                                 const int *__restrict__ dflag) {
  const int F = *dflag;
  int bid = blockIdx.x;
  int t = bid >> 4, b = bid & 15;
  int tid = threadIdx.x;
  __shared__ float xl[PREN];
  xl[tid] = bf2f(x1[(t * BB + b) * PREN + tid]);
  __syncthreads();
  int j = tid;
  float acc = 0.f;
  for (int k = 0; k < PREN; ++k) acc += xl[k] * ldin(W2, (size_t)k * PREN + j, F);
  acc = fmaxf(acc, 0.f);
  uint32_t idx = ((uint32_t)(t * BB + b)) * PREN + (uint32_t)j;
  acc = keep_mask(k0, k1, idx) ? acc * 2.f : 0.f;
  preT[(t * PREN + j) * BB + b] = acc;
}

// ---------------- pm = memory @ Wmem (stored bf16) ----------------
__global__ __launch_bounds__(128) void k_pm(const void *__restrict__ memory,
                                            const void *__restrict__ Wmem,
                                            u16 *__restrict__ pm,
                                            const int *__restrict__ dflag) {
  const int F = *dflag;
  int bid = blockIdx.x;  // b*TENC + tt
  int tid = threadIdx.x;
  __shared__ float ml[EDIM];
  for (int e = tid; e < EDIM; e += 128) ml[e] = ldin(memory, (size_t)bid * EDIM + e, F);
  __syncthreads();
  int j = tid;
  float acc = 0.f;
  for (int e = 0; e < EDIM; ++e) acc += ml[e] * ldin(Wmem, (size_t)e * ATTN + j, F);
  pm[(size_t)bid * ATTN + j] = f2bf(acc);
}

// ---------------- split-K LSTM pre-activation GEMM (chunk = 256) ----------------
__global__ __launch_bounds__(256) void k_zgemm(const void *__restrict__ Wih,
                                               const void *__restrict__ Whh,
                                               const float *__restrict__ segA, int lenA,
                                               const float *__restrict__ segB, int lenB,
                                               const float *__restrict__ segC,
                                               float *__restrict__ zp,
                                               const int *__restrict__ dflag) {
  const int F = *dflag;
  int col = blockIdx.x * 256 + threadIdx.x;
  int kc = blockIdx.y;
  int kbase = kc * 256;
  int lenAB = lenA + lenB;
  const float *xT; const void *W; int wrow;
  if (kbase < lenA)       { xT = segA + kbase * BB;           W = Wih; wrow = kbase; }
  else if (kbase < lenAB) { xT = segB + (kbase - lenA) * BB;  W = Wih; wrow = kbase; }
  else                    { xT = segC + (kbase - lenAB) * BB; W = Whh; wrow = kbase - lenAB; }
  float4 s0 = {0, 0, 0, 0}, s1 = {0, 0, 0, 0}, s2 = {0, 0, 0, 0}, s3 = {0, 0, 0, 0};
  for (int kk = 0; kk < 256; ++kk) {
    float w = ldin(W, (size_t)(wrow + kk) * 4096 + col, F);
    const float4 *xr = (const float4 *)(xT + kk * BB);
    float4 a0 = xr[0], a1 = xr[1], a2 = xr[2], a3 = xr[3];
    s0.x += a0.x * w; s0.y += a0.y * w; s0.z += a0.z * w; s0.w += a0.w * w;
    s1.x += a1.x * w; s1.y += a1.y * w; s1.z += a1.z * w; s1.w += a1.w * w;
    s2.x += a2.x * w; s2.y += a2.y * w; s2.z += a2.z * w; s2.w += a2.w * w;
    s3.x += a3.x * w; s3.y += a3.y * w; s3.z += a3.z * w; s3.w += a3.w * w;
  }
  float *zo = zp + ((size_t)kc * BB) * 4096 + col;
  zo[0 * 4096] = s0.x; zo[1 * 4096] = s0.y; zo[2 * 4096] = s0.z; zo[3 * 4096] = s0.w;
  zo[4 * 4096] = s1.x; zo[5 * 4096] = s1.y; zo[6 * 4096] = s1.z; zo[7 * 4096] = s1.w;
  zo[8 * 4096] = s2.x; zo[9 * 4096] = s2.y; zo[10 * 4096] = s2.z; zo[11 * 4096] = s2.w;
  zo[12 * 4096] = s3.x; zo[13 * 4096] = s3.y; zo[14 * 4096] = s3.z; zo[15 * 4096] = s3.w;
}

// ---------------- LSTM activation: reduce partials -> h,c ----------------
__global__ __launch_bounds__(256) void k_act(const float *__restrict__ zp, int nch,
                                             const void *__restrict__ bias,
                                             float *__restrict__ h, float *__restrict__ hT,
                                             float *__restrict__ c,
                                             const int *__restrict__ dflag) {
  const int F = *dflag;
  int bid = blockIdx.x;
  int b = bid >> 2;
  int u = (bid & 3) * 256 + threadIdx.x;
  float zi = 0.f, zf = 0.f, zg = 0.f, zo = 0.f;
  for (int kc = 0; kc < nch; ++kc) {
    const float *z = zp + ((size_t)kc * BB + b) * 4096;
    zi += z[u]; zf += z[u + 1024]; zg += z[u + 2048]; zo += z[u + 3072];
  }
  zi += ldin(bias, u, F); zf += ldin(bias, u + 1024, F);
  zg += ldin(bias, u + 2048, F); zo += ldin(bias, u + 3072, F);
  float cn = sigm(zf) * c[b * 1024 + u] + sigm(zi) * tanhf(zg);
  float hn = sigm(zo) * tanhf(cn);
  c[b * 1024 + u] = cn;
  h[b * 1024 + u] = hn;
  hT[u * BB + b] = hn;
}

// ---------------- fused attention (one block per batch row) ----------------
__global__ __launch_bounds__(1024) void k_att(const float *__restrict__ ah,
                                              float *__restrict__ aw, float *__restrict__ awc,
                                              const u16 *__restrict__ pm,
                                              const void *__restrict__ Wq,
                                              const void *__restrict__ vw,
                                              const void *__restrict__ convW,
                                              const void *__restrict__ ldW,
                                              const void *__restrict__ memory,
                                              const int *__restrict__ mlen,
                                              float *__restrict__ ctx, float *__restrict__ ctxT,
                                              void *__restrict__ out, size_t algn_off, int t,
                                              const int *__restrict__ dflag) {
  const int F = *dflag;
  int b = blockIdx.x;
  int tid = threadIdx.x;
  __shared__ float ah_l[ARN];
  __shared__ float aw_l[288], awc_l[288];
  __shared__ float lc[TENC * 33];
  __shared__ float pqp[ATTN * 8];
  __shared__ float pq[ATTN];
  __shared__ float ep[TENC * 4];
  __shared__ float e_l[TENC];
  __shared__ float red[32];
  __shared__ float s_max, s_inv;

  ah_l[tid] = ah[b * ARN + tid];
  if (tid < TENC) { aw_l[16 + tid] = aw[b * TENC + tid]; awc_l[16 + tid] = awc[b * TENC + tid]; }
  if (tid < 16) { aw_l[tid] = 0.f; aw_l[272 + tid] = 0.f; awc_l[tid] = 0.f; awc_l[272 + tid] = 0.f; }
  __syncthreads();

  {
    int j = tid & 127, kc = tid >> 7;
    float a = 0.f;
    for (int kk = 0; kk < 128; ++kk)
      a += ah_l[kc * 128 + kk] * ldin(Wq, (size_t)(kc * 128 + kk) * ATTN + j, F);
    pqp[j * 8 + kc] = a;
  }
  __syncthreads();
  if (tid < ATTN) {
    float s = 0.f;
#pragma unroll
    for (int kc = 0; kc < 8; ++kc) s += pqp[tid * 8 + kc];
    pq[tid] = s;
  }
  {
    int tt = tid & 255, fg = tid >> 8;
    float acc8[8] = {0, 0, 0, 0, 0, 0, 0, 0};
    for (int k = 0; k < KSIZE; ++k) {
      float a = aw_l[tt + k + 1];
      float cc = awc_l[tt + k + 1];
#pragma unroll
      for (int f8 = 0; f8 < 8; ++f8) {
        int f = fg * 8 + f8;
        acc8[f8] += a * ldin(convW, (size_t)f * 62 + k, F) + cc * ldin(convW, (size_t)f * 62 + 31 + k, F);
      }
    }
#pragma unroll
    for (int f8 = 0; f8 < 8; ++f8) lc[tt * 33 + fg * 8 + f8] = acc8[f8];
  }
  __syncthreads();
  {
    int tt = tid & 255, jg = tid >> 8;
    float esum = 0.f;
    const u16 *pmrow = pm + ((size_t)(b * TENC + tt)) * ATTN;
    for (int jj = 0; jj < 32; ++jj) {
      int j = jg * 32 + jj;
      float s = pq[j] + bf2f(pmrow[j]);
#pragma unroll
      for (int f = 0; f < NFILT; ++f) s += lc[tt * 33 + f] * ldin(ldW, (size_t)f * ATTN + j, F);
      esum += tanhf(s) * ldin(vw, j, F);
    }
    ep[tt * 4 + jg] = esum;
  }
  __syncthreads();
  int len = mlen[b];
  if (tid < TENC) {
    float e = ep[tid * 4] + ep[tid * 4 + 1] + ep[tid * 4 + 2] + ep[tid * 4 + 3];
    if (tid >= len) e = -1e9f;
    e_l[tid] = e;
  }
  __syncthreads();
  if (tid < 32) {
    float m = -1e30f;
#pragma unroll
    for (int i = 0; i < 8; ++i) m = fmaxf(m, e_l[tid * 8 + i]);
    red[tid] = m;
  }
  __syncthreads();
  if (tid == 0) {
    float m = -1e30f;
    for (int i = 0; i < 32; ++i) m = fmaxf(m, red[i]);
    s_max = m;
  }
  __syncthreads();
  if (tid < TENC) e_l[tid] = expf(e_l[tid] - s_max);
  __syncthreads();
  if (tid < 32) {
    float s = 0.f;
#pragma unroll
    for (int i = 0; i < 8; ++i) s += e_l[tid * 8 + i];
    red[tid] = s;
  }
  __syncthreads();
  if (tid == 0) {
    float s = 0.f;
    for (int i = 0; i < 32; ++i) s += red[i];
    s_inv = 1.f / s;
  }
  __syncthreads();
  if (tid < TENC) {
    float w = e_l[tid] * s_inv;
    e_l[tid] = w;
    aw[b * TENC + tid] = w;
    awc[b * TENC + tid] = awc_l[16 + tid] + w;
    stf(out, algn_off + ((size_t)b * TDEC + t) * TENC + tid, w, F);
  }
  __syncthreads();
  if (tid < EDIM) {
    int e = tid;
    float a = 0.f;
    for (int tt = 0; tt < len; ++tt)
      a += e_l[tt] * ldin(memory, ((size_t)b * TENC + tt) * EDIM + e, F);
    ctx[b * EDIM + e] = a;
    ctxT[e * BB + b] = a;
  }
}

// ---------------- output projection: mel + gate ----------------
__global__ __launch_bounds__(256) void k_out(const float *__restrict__ dh,
                                             const float *__restrict__ ctx,
                                             const void *__restrict__ projW,
                                             const void *__restrict__ projB,
                                             const void *__restrict__ gateW,
                                             const void *__restrict__ gateB,
                                             void *__restrict__ out, size_t gate_off, int t,
                                             const int *__restrict__ dflag) {
  const int F = *dflag;
  int b = blockIdx.x;
  int tid = threadIdx.x;
  __shared__ float xl[1536];
  __shared__ float part[3 * 81];
  for (int i = tid; i < 1536; i += 256)
    xl[i] = (i < 1024) ? dh[b * 1024 + i] : ctx[b * EDIM + (i - 1024)];
  __syncthreads();
  if (tid < 243) {
    int col = tid % 81;
    int kc = tid / 81;
    float a = 0.f;
    for (int kk = 0; kk < 512; ++kk) {
      int k = kc * 512 + kk;
      float wv = (col < 80) ? ldin(projW, (size_t)k * NMELS + col, F) : ldin(gateW, k, F);
      a += xl[k] * wv;
    }
    part[kc * 81 + col] = a;
  }
  __syncthreads();
  if (tid < 81) {
    float s = part[tid] + part[81 + tid] + part[162 + tid];
    if (tid < 80) {
      s += ldin(projB, tid, F);
      stf(out, ((size_t)b * NMELS + tid) * TDEC + t, s, F);
    } else {
      s += ldin(gateB, 0, F);
      stf(out, gate_off + (size_t)b * TDEC + t, s, F);
    }
  }
}

extern "C" void kernel_launch(void *const *d_in, const int *in_sizes, int n_in,
                              void *d_out, int out_size, void *d_ws, size_t ws_size,
                              hipStream_t stream) {
  (void)in_sizes; (void)n_in; (void)out_size; (void)ws_size;
  const void *memory = d_in[0];
  const void *dec_in = d_in[1];
  const int  *mlen   = (const int *)d_in[2];
  const void *pw1    = d_in[3];
  const void *pw2    = d_in[4];
  const void *aWih   = d_in[5];
  const void *aWhh   = d_in[6];
  const void *ab     = d_in[7];
  const void *wq     = d_in[8];
  const void *wmem   = d_in[9];
  const void *vw     = d_in[10];
  const void *convW  = d_in[11];
  const void *ldW    = d_in[12];
  const void *dWih   = d_in[13];
  const void *dWhh   = d_in[14];
  const void *db     = d_in[15];
  const void *projW  = d_in[16];
  const void *projB  = d_in[17];
  const void *gateW  = d_in[18];
  const void *gateB  = d_in[19];

  const size_t GATE_OFF = (size_t)16 * 80 * 200;  // 256000
  const size_t ALGN_OFF = GATE_OFF + 16 * 200;    // 259200

  // workspace layout (floats), total ~7.44 MB:
  float *ws = (float *)d_ws;
  float *st   = ws;                         // 122880 state floats
  float *preT = ws + 122880;                // 819200 f32
  u16   *pmu  = (u16 *)(ws + 942080);       // 524288 u16 (= 262144 floats)
  float *z    = ws + 1204224;               // 655360 f32 (shared aLSTM/dLSTM partials)
  u16   *x1u  = (u16 *)(ws + 1204224);      // 819200 u16, aliased on z (pre-loop only)
  int   *dflag = (int *)(ws + 1859584);

  float *ah  = st;
  float *ahT = ah + 16384;
  float *ac  = ahT + 16384;
  float *dh  = ac + 16384;
  float *dhT = dh + 16384;
  float *dc  = dhT + 16384;
  float *ctx = dc + 16384;
  float *ctxT = ctx + 8192;
  float *aw   = ctxT + 8192;
  float *awc  = aw + 4096;
  size_t state_floats = 122880;

  hipMemsetAsync(st, 0, state_floats * sizeof(float), stream);

  uint32_t K1a, K1b, K2a, K2b;
#if MASK_PARTITIONABLE
  tf2x32(0u, 42u, 0u, 0u, K1a, K1b);
  tf2x32(0u, 42u, 0u, 1u, K2a, K2b);
#else
  {
    uint32_t a0, b0, a1, b1;
    tf2x32(0u, 42u, 0u, 2u, a0, b0);
    tf2x32(0u, 42u, 1u, 3u, a1, b1);
    K1a = a0; K1b = a1; K2a = b0; K2b = b1;
  }
#endif

  k_detect<<<1, 64, 0, stream>>>(memory, dflag);
  k_prenet1<<<TDEC * BB, 256, 0, stream>>>(dec_in, pw1, x1u, K1a, K1b, dflag);
  k_prenet2<<<TDEC * BB, 256, 0, stream>>>(x1u, pw2, preT, K2a, K2b, dflag);
  k_pm<<<BB * TENC, 128, 0, stream>>>(memory, wmem, pmu, dflag);

  for (int t = 0; t < TDEC; ++t) {
    k_zgemm<<<dim3(16, 7), 256, 0, stream>>>(aWih, aWhh,
                                             preT + (size_t)t * PREN * BB, PREN,
                                             ctxT, EDIM, ahT, z, dflag);
    k_act<<<64, 256, 0, stream>>>(z, 7, ab, ah, ahT, ac, dflag);
    k_att<<<16, 1024, 0, stream>>>(ah, aw, awc, pmu, wq, vw, convW, ldW,
                                   memory, mlen, ctx, ctxT, d_out, ALGN_OFF, t, dflag);
    k_zgemm<<<dim3(16, 10), 256, 0, stream>>>(dWih, dWhh,
                                              ahT, ARN, ctxT, EDIM, dhT, z, dflag);
    k_act<<<64, 256, 0, stream>>>(z, 10, db, dh, dhT, dc, dflag);
    k_out<<<16, 256, 0, stream>>>(dh, ctx, projW, projB, gateW, gateB,
                                  d_out, GATE_OFF, t, dflag);
  }
}

// Round 5
// 45417.587 us; speedup vs baseline: 1.7213x; 1.7213x over previous
//
#include <hip/hip_runtime.h>
#include <stdint.h>

typedef unsigned short u16;

#define BB    16
#define TENC  256
#define TDEC  200
#define NMELS 80
#define EDIM  512
#define PREN  256
#define ARN   1024
#define ATTN  128
#define NFILT 32
#define KSIZE 31

__host__ __device__ inline void tf2x32(uint32_t k0, uint32_t k1, uint32_t x0, uint32_t x1,
                                       uint32_t &y0, uint32_t &y1) {
  uint32_t ks2 = k0 ^ k1 ^ 0x1BD11BDAu;
  x0 += k0; x1 += k1;
  const int R0[4] = {13, 15, 26, 6};
  const int R1[4] = {17, 29, 16, 24};
#pragma unroll
  for (int g = 0; g < 5; ++g) {
    const int *R = (g & 1) ? R1 : R0;
#pragma unroll
    for (int i = 0; i < 4; ++i) {
      x0 += x1;
      x1 = (x1 << R[i]) | (x1 >> (32 - R[i]));
      x1 ^= x0;
    }
    switch (g) {
      case 0: x0 += k1;  x1 += ks2 + 1u; break;
      case 1: x0 += ks2; x1 += k0 + 2u;  break;
      case 2: x0 += k0;  x1 += k1 + 3u;  break;
      case 3: x0 += k1;  x1 += ks2 + 4u; break;
      case 4: x0 += ks2; x1 += k0 + 5u;  break;
    }
  }
  y0 = x0; y1 = x1;
}

__device__ inline bool keep_mask(uint32_t k0, uint32_t k1, uint32_t idx) {
  uint32_t y0, y1;
  tf2x32(k0, k1, 0u, idx, y0, y1);
  return (((y0 ^ y1) >> 31) == 0u);
}

__device__ inline float bf2f(u16 v) {
  union { uint32_t u; float f; } x;
  x.u = ((uint32_t)v) << 16;
  return x.f;
}
__device__ inline u16 f2bf(float f) {
  union { float f; uint32_t u; } x;
  x.f = f;
  uint32_t r = ((x.u >> 16) & 1u) + 0x7FFFu;
  return (u16)((x.u + r) >> 16);
}
__device__ inline float sigm(float x) { return 1.f / (1.f + expf(-x)); }

// ---------------- prenet layer 1: x1(bf16) = mask1(relu(di @ W1)) * 2 ----------------
__global__ __launch_bounds__(256) void k_prenet1(const float *__restrict__ dec_in,
                                                 const float *__restrict__ W1,
                                                 u16 *__restrict__ x1,
                                                 uint32_t k0, uint32_t k1) {
  int bid = blockIdx.x;
  int t = bid >> 4, b = bid & 15;
  int tid = threadIdx.x;
  __shared__ float di[NMELS];
  if (tid < NMELS)
    di[tid] = (t == 0) ? 0.f : dec_in[((size_t)b * NMELS + tid) * TDEC + (t - 1)];
  __syncthreads();
  int j = tid;
  float acc = 0.f;
#pragma unroll 4
  for (int m = 0; m < NMELS; ++m) acc += di[m] * W1[(size_t)m * PREN + j];
  acc = fmaxf(acc, 0.f);
  uint32_t idx = ((uint32_t)(t * BB + b)) * PREN + (uint32_t)j;
  acc = keep_mask(k0, k1, idx) ? acc * 2.f : 0.f;
  x1[(t * BB + b) * PREN + j] = f2bf(acc);
}

// ---------------- prenet layer 2 -> preT (f32, [t][j][b]) ----------------
__global__ __launch_bounds__(256) void k_prenet2(const u16 *__restrict__ x1,
                                                 const float *__restrict__ W2,
                                                 float *__restrict__ preT,
                                                 uint32_t k0, uint32_t k1) {
  int bid = blockIdx.x;
  int t = bid >> 4, b = bid & 15;
  int tid = threadIdx.x;
  __shared__ float xl[PREN];
  xl[tid] = bf2f(x1[(t * BB + b) * PREN + tid]);
  __syncthreads();
  int j = tid;
  float acc = 0.f;
#pragma unroll 4
  for (int k = 0; k < PREN; ++k) acc += xl[k] * W2[(size_t)k * PREN + j];
  acc = fmaxf(acc, 0.f);
  uint32_t idx = ((uint32_t)(t * BB + b)) * PREN + (uint32_t)j;
  acc = keep_mask(k0, k1, idx) ? acc * 2.f : 0.f;
  preT[(t * PREN + j) * BB + b] = acc;
}

// ---------------- pm = memory @ Wmem (stored bf16) ----------------
__global__ __launch_bounds__(128) void k_pm(const float *__restrict__ memory,
                                            const float *__restrict__ Wmem,
                                            u16 *__restrict__ pm) {
  int bid = blockIdx.x;  // b*TENC + tt
  int tid = threadIdx.x;
  __shared__ float ml[EDIM];
  ((float4 *)ml)[tid] = ((const float4 *)(memory + (size_t)bid * EDIM))[tid];
  __syncthreads();
  int j = tid;
  float acc = 0.f;
#pragma unroll 4
  for (int e = 0; e < EDIM; ++e) acc += ml[e] * Wmem[(size_t)e * ATTN + j];
  pm[(size_t)bid * ATTN + j] = f2bf(acc);
}

// ---------------- split-K LSTM pre-activation GEMM (chunk = 256, 128 thr, 32 col-blocks) ----------------
// z[kc][b][col] partial; x sources held transposed [k][16]
__global__ __launch_bounds__(128) void k_zgemm(const float *__restrict__ Wih,
                                               const float *__restrict__ Whh,
                                               const float *__restrict__ segA, int lenA,
                                               const float *__restrict__ segB, int lenB,
                                               const float *__restrict__ segC,
                                               float *__restrict__ zp) {
  __shared__ float xs[256 * 16];
  int tid = threadIdx.x;
  int col = blockIdx.x * 128 + tid;
  int kc = blockIdx.y;
  int kbase = kc * 256;
  int lenAB = lenA + lenB;
  const float *xT; const float *W; int wrow;
  if (kbase < lenA)       { xT = segA + (size_t)kbase * BB;           W = Wih; wrow = kbase; }
  else if (kbase < lenAB) { xT = segB + (size_t)(kbase - lenA) * BB;  W = Wih; wrow = kbase; }
  else                    { xT = segC + (size_t)(kbase - lenAB) * BB; W = Whh; wrow = kbase - lenAB; }
#pragma unroll
  for (int i = 0; i < 8; ++i)
    ((float4 *)xs)[tid + i * 128] = ((const float4 *)xT)[tid + i * 128];
  __syncthreads();
  const float *wp = W + (size_t)wrow * 4096 + col;
  float4 s0 = {0, 0, 0, 0}, s1 = {0, 0, 0, 0}, s2 = {0, 0, 0, 0}, s3 = {0, 0, 0, 0};
#pragma unroll 4
  for (int kk = 0; kk < 256; ++kk) {
    float w = wp[(size_t)kk * 4096];
    const float4 *xr = (const float4 *)(xs + kk * 16);
    float4 a0 = xr[0], a1 = xr[1], a2 = xr[2], a3 = xr[3];
    s0.x += a0.x * w; s0.y += a0.y * w; s0.z += a0.z * w; s0.w += a0.w * w;
    s1.x += a1.x * w; s1.y += a1.y * w; s1.z += a1.z * w; s1.w += a1.w * w;
    s2.x += a2.x * w; s2.y += a2.y * w; s2.z += a2.z * w; s2.w += a2.w * w;
    s3.x += a3.x * w; s3.y += a3.y * w; s3.z += a3.z * w; s3.w += a3.w * w;
  }
  float *zo = zp + ((size_t)kc * BB) * 4096 + col;
  zo[0 * 4096] = s0.x; zo[1 * 4096] = s0.y; zo[2 * 4096] = s0.z; zo[3 * 4096] = s0.w;
  zo[4 * 4096] = s1.x; zo[5 * 4096] = s1.y; zo[6 * 4096] = s1.z; zo[7 * 4096] = s1.w;
  zo[8 * 4096] = s2.x; zo[9 * 4096] = s2.y; zo[10 * 4096] = s2.z; zo[11 * 4096] = s2.w;
  zo[12 * 4096] = s3.x; zo[13 * 4096] = s3.y; zo[14 * 4096] = s3.z; zo[15 * 4096] = s3.w;
}

// ---------------- fused aLSTM-activation + attention (one block per batch row) ----------------
__global__ __launch_bounds__(1024) void k_att(const float *__restrict__ z1p,
                                              const float *__restrict__ ab,
                                              float *__restrict__ ac,
                                              float *__restrict__ ahT,
                                              float *__restrict__ aw, float *__restrict__ awc,
                                              const u16 *__restrict__ pm,
                                              const float *__restrict__ Wq,
                                              const float *__restrict__ vw,
                                              const float *__restrict__ convW,
                                              const float *__restrict__ ldW,
                                              const float *__restrict__ memory,
                                              const int *__restrict__ mlen,
                                              float *__restrict__ ctx, float *__restrict__ ctxT,
                                              float *__restrict__ align_out, int t) {
  int b = blockIdx.x;
  int tid = threadIdx.x;
  __shared__ float ah_l[ARN];
  __shared__ float aw_l[288], awc_l[288];
  __shared__ float lc[TENC * 33];
  __shared__ float pqp[ATTN * 8];
  __shared__ float pq[ATTN];
  __shared__ float ep[TENC * 4];
  __shared__ float e_l[TENC];
  __shared__ float cp[2][EDIM];
  __shared__ float red[32];
  __shared__ float s_max, s_inv;

  // ---- phase A: reduce z1 partials -> ah (LSTM activation) ----
  {
    int u = tid;
    float zi = 0.f, zf = 0.f, zg = 0.f, zo = 0.f;
#pragma unroll
    for (int kc = 0; kc < 7; ++kc) {
      const float *z = z1p + ((size_t)kc * BB + b) * 4096;
      zi += z[u]; zf += z[u + 1024]; zg += z[u + 2048]; zo += z[u + 3072];
    }
    zi += ab[u]; zf += ab[u + 1024]; zg += ab[u + 2048]; zo += ab[u + 3072];
    float cn = sigm(zf) * ac[b * 1024 + u] + sigm(zi) * tanhf(zg);
    float hn = sigm(zo) * tanhf(cn);
    ac[b * 1024 + u] = cn;
    ahT[u * BB + b] = hn;
    ah_l[u] = hn;
  }
  if (tid < TENC) { aw_l[16 + tid] = aw[b * TENC + tid]; awc_l[16 + tid] = awc[b * TENC + tid]; }
  if (tid < 16) { aw_l[tid] = 0.f; aw_l[272 + tid] = 0.f; awc_l[tid] = 0.f; awc_l[272 + tid] = 0.f; }
  __syncthreads();

  // ---- pq = ah @ Wq (partials over 8 k-chunks) ----
  {
    int j = tid & 127, kc = tid >> 7;
    float a = 0.f;
    const float *wq = Wq + (size_t)(kc * 128) * ATTN + j;
#pragma unroll 4
    for (int kk = 0; kk < 128; ++kk) a += ah_l[kc * 128 + kk] * wq[(size_t)kk * ATTN];
    pqp[j * 8 + kc] = a;
  }
  __syncthreads();
  if (tid < ATTN) {
    float s = 0.f;
#pragma unroll
    for (int kc = 0; kc < 8; ++kc) s += pqp[tid * 8 + kc];
    pq[tid] = s;
  }
  // ---- location conv ----
  {
    int tt = tid & 255, fg = tid >> 8;
    float acc8[8] = {0, 0, 0, 0, 0, 0, 0, 0};
    for (int k = 0; k < KSIZE; ++k) {
      float a = aw_l[tt + k + 1];
      float cc = awc_l[tt + k + 1];
#pragma unroll
      for (int f8 = 0; f8 < 8; ++f8) {
        int f = fg * 8 + f8;
        acc8[f8] += a * convW[(size_t)f * 62 + k] + cc * convW[(size_t)f * 62 + 31 + k];
      }
    }
#pragma unroll
    for (int f8 = 0; f8 < 8; ++f8) lc[tt * 33 + fg * 8 + f8] = acc8[f8];
  }
  __syncthreads();
  // ---- energies ----
  {
    int tt = tid & 255, jg = tid >> 8;
    float esum = 0.f;
    const u16 *pmrow = pm + ((size_t)(b * TENC + tt)) * ATTN;
    for (int jj = 0; jj < 32; ++jj) {
      int j = jg * 32 + jj;
      float s = pq[j] + bf2f(pmrow[j]);
#pragma unroll
      for (int f = 0; f < NFILT; ++f) s += lc[tt * 33 + f] * ldW[(size_t)f * ATTN + j];
      esum += tanhf(s) * vw[j];
    }
    ep[tt * 4 + jg] = esum;
  }
  __syncthreads();
  int len = mlen[b];
  if (tid < TENC) {
    float e = ep[tid * 4] + ep[tid * 4 + 1] + ep[tid * 4 + 2] + ep[tid * 4 + 3];
    if (tid >= len) e = -1e9f;
    e_l[tid] = e;
  }
  __syncthreads();
  if (tid < 32) {
    float m = -1e30f;
#pragma unroll
    for (int i = 0; i < 8; ++i) m = fmaxf(m, e_l[tid * 8 + i]);
    red[tid] = m;
  }
  __syncthreads();
  if (tid == 0) {
    float m = -1e30f;
    for (int i = 0; i < 32; ++i) m = fmaxf(m, red[i]);
    s_max = m;
  }
  __syncthreads();
  if (tid < TENC) e_l[tid] = expf(e_l[tid] - s_max);
  __syncthreads();
  if (tid < 32) {
    float s = 0.f;
#pragma unroll
    for (int i = 0; i < 8; ++i) s += e_l[tid * 8 + i];
    red[tid] = s;
  }
  __syncthreads();
  if (tid == 0) {
    float s = 0.f;
    for (int i = 0; i < 32; ++i) s += red[i];
    s_inv = 1.f / s;
  }
  __syncthreads();
  if (tid < TENC) {
    float w = e_l[tid] * s_inv;
    e_l[tid] = w;
    aw[b * TENC + tid] = w;
    awc[b * TENC + tid] = awc_l[16 + tid] + w;
    align_out[((size_t)b * TDEC + t) * TENC + tid] = w;
  }
  __syncthreads();
  // ---- ctx = w @ memory, split over tt halves ----
  {
    int e = tid & 511, h = tid >> 9;
    int t0 = h * 128, t1 = min(len, (h + 1) * 128);
    float a = 0.f;
    for (int tt = t0; tt < t1; ++tt)
      a += e_l[tt] * memory[((size_t)b * TENC + tt) * EDIM + e];
    cp[h][e] = a;
  }
  __syncthreads();
  if (tid < EDIM) {
    float v = cp[0][tid] + cp[1][tid];
    ctx[b * EDIM + tid] = v;
    ctxT[tid * BB + b] = v;
  }
}

// ---------------- fused dLSTM-activation + projection ----------------
__global__ __launch_bounds__(256) void k_out(const float *__restrict__ z2p,
                                             const float *__restrict__ db,
                                             float *__restrict__ dc,
                                             float *__restrict__ dhT,
                                             const float *__restrict__ ctx,
                                             const float *__restrict__ projW,
                                             const float *__restrict__ projB,
                                             const float *__restrict__ gateW,
                                             const float *__restrict__ gateB,
                                             float *__restrict__ mel_out,
                                             float *__restrict__ gate_out, int t) {
  int b = blockIdx.x;
  int tid = threadIdx.x;
  __shared__ float xl[1536];
  __shared__ float part[3 * 81];
  // ---- phase A: reduce z2 partials -> dh ----
#pragma unroll
  for (int r = 0; r < 4; ++r) {
    int u = r * 256 + tid;
    float zi = 0.f, zf = 0.f, zg = 0.f, zo = 0.f;
#pragma unroll
    for (int kc = 0; kc < 10; ++kc) {
      const float *z = z2p + ((size_t)kc * BB + b) * 4096;
      zi += z[u]; zf += z[u + 1024]; zg += z[u + 2048]; zo += z[u + 3072];
    }
    zi += db[u]; zf += db[u + 1024]; zg += db[u + 2048]; zo += db[u + 3072];
    float cn = sigm(zf) * dc[b * 1024 + u] + sigm(zi) * tanhf(zg);
    float hn = sigm(zo) * tanhf(cn);
    dc[b * 1024 + u] = cn;
    dhT[u * BB + b] = hn;
    xl[u] = hn;
  }
  for (int i = tid; i < EDIM; i += 256) xl[1024 + i] = ctx[b * EDIM + i];
  __syncthreads();
  // ---- phase B: projection ----
  if (tid < 243) {
    int col = tid % 81;
    int kc = tid / 81;
    float a = 0.f;
#pragma unroll 4
    for (int kk = 0; kk < 512; ++kk) {
      int k = kc * 512 + kk;
      float wv = (col < 80) ? projW[(size_t)k * NMELS + col] : gateW[k];
      a += xl[k] * wv;
    }
    part[kc * 81 + col] = a;
  }
  __syncthreads();
  if (tid < 81) {
    float s = part[tid] + part[81 + tid] + part[162 + tid];
    if (tid < 80) {
      s += projB[tid];
      mel_out[((size_t)b * NMELS + tid) * TDEC + t] = s;
    } else {
      s += gateB[0];
      gate_out[(size_t)b * TDEC + t] = s;
    }
  }
}

extern "C" void kernel_launch(void *const *d_in, const int *in_sizes, int n_in,
                              void *d_out, int out_size, void *d_ws, size_t ws_size,
                              hipStream_t stream) {
  (void)in_sizes; (void)n_in; (void)out_size; (void)ws_size;
  const float *memory = (const float *)d_in[0];
  const float *dec_in = (const float *)d_in[1];
  const int   *mlen   = (const int *)d_in[2];
  const float *pw1    = (const float *)d_in[3];
  const float *pw2    = (const float *)d_in[4];
  const float *aWih   = (const float *)d_in[5];
  const float *aWhh   = (const float *)d_in[6];
  const float *ab     = (const float *)d_in[7];
  const float *wq     = (const float *)d_in[8];
  const float *wmem   = (const float *)d_in[9];
  const float *vw     = (const float *)d_in[10];
  const float *convW  = (const float *)d_in[11];
  const float *ldW    = (const float *)d_in[12];
  const float *dWih   = (const float *)d_in[13];
  const float *dWhh   = (const float *)d_in[14];
  const float *db     = (const float *)d_in[15];
  const float *projW  = (const float *)d_in[16];
  const float *projB  = (const float *)d_in[17];
  const float *gateW  = (const float *)d_in[18];
  const float *gateB  = (const float *)d_in[19];

  float *out_mel  = (float *)d_out;
  float *out_gate = out_mel + (size_t)16 * 80 * 200;
  float *out_algn = out_gate + (size_t)16 * 200;

  // workspace (floats), total ~7.31 MB
  // state block (must be zeroed EVERY call): ahT,ac,dhT,dc (4*16384) + ctx,ctxT (2*8192)
  //   + aw,awc (2*4096) = 90112 floats.  R4 bug: memset was 77824 -> aw/awc garbage.
  const size_t STATE_FLOATS = 90112;
  float *ws = (float *)d_ws;
  float *st   = ws;                          // 90112 state floats
  float *preT = ws + 90112;                  // 819200
  u16   *pmu  = (u16 *)(ws + 909312);        // 524288 u16 (262144 f)
  float *z    = ws + 1171456;                // 655360 (shared z1p/z2p)
  u16   *x1u  = (u16 *)z;                    // 819200 u16 aliased (pre-loop only)

  float *ahT  = st;
  float *ac   = ahT + 16384;
  float *dhT  = ac + 16384;
  float *dc   = dhT + 16384;
  float *ctx  = dc + 16384;
  float *ctxT = ctx + 8192;
  float *aw   = ctxT + 8192;
  float *awc  = aw + 4096;

  hipMemsetAsync(st, 0, STATE_FLOATS * sizeof(float), stream);

  uint32_t K1a, K1b, K2a, K2b;
  tf2x32(0u, 42u, 0u, 0u, K1a, K1b);
  tf2x32(0u, 42u, 0u, 1u, K2a, K2b);

  k_prenet1<<<TDEC * BB, 256, 0, stream>>>(dec_in, pw1, x1u, K1a, K1b);
  k_prenet2<<<TDEC * BB, 256, 0, stream>>>(x1u, pw2, preT, K2a, K2b);
  k_pm<<<BB * TENC, 128, 0, stream>>>(memory, wmem, pmu);

  for (int t = 0; t < TDEC; ++t) {
    // attention LSTM pre-act: [pre_t(256) | ctx(512) | ah(1024)] -> 7 chunks of 256
    k_zgemm<<<dim3(32, 7), 128, 0, stream>>>(aWih, aWhh,
                                             preT + (size_t)t * PREN * BB, PREN,
                                             ctxT, EDIM, ahT, z);
    k_att<<<16, 1024, 0, stream>>>(z, ab, ac, ahT, aw, awc, pmu, wq, vw, convW, ldW,
                                   memory, mlen, ctx, ctxT, out_algn, t);
    // decoder LSTM pre-act: [ah(1024) | ctx(512) | dh(1024)] -> 10 chunks of 256
    k_zgemm<<<dim3(32, 10), 128, 0, stream>>>(dWih, dWhh,
                                              ahT, ARN, ctxT, EDIM, dhT, z);
    k_out<<<16, 256, 0, stream>>>(z, db, dc, dhT, ctx, projW, projB, gateW, gateB,
                                  out_mel, out_gate, t);
  }
}

// Round 6
// 43955.466 us; speedup vs baseline: 1.7786x; 1.0333x over previous
//
#include <hip/hip_runtime.h>
#include <stdint.h>

typedef unsigned short u16;

#define BB    16
#define TENC  256
#define TDEC  200
#define NMELS 80
#define EDIM  512
#define PREN  256
#define ARN   1024
#define ATTN  128
#define NFILT 32
#define KSIZE 31

__host__ __device__ inline void tf2x32(uint32_t k0, uint32_t k1, uint32_t x0, uint32_t x1,
                                       uint32_t &y0, uint32_t &y1) {
  uint32_t ks2 = k0 ^ k1 ^ 0x1BD11BDAu;
  x0 += k0; x1 += k1;
  const int R0[4] = {13, 15, 26, 6};
  const int R1[4] = {17, 29, 16, 24};
#pragma unroll
  for (int g = 0; g < 5; ++g) {
    const int *R = (g & 1) ? R1 : R0;
#pragma unroll
    for (int i = 0; i < 4; ++i) {
      x0 += x1;
      x1 = (x1 << R[i]) | (x1 >> (32 - R[i]));
      x1 ^= x0;
    }
    switch (g) {
      case 0: x0 += k1;  x1 += ks2 + 1u; break;
      case 1: x0 += ks2; x1 += k0 + 2u;  break;
      case 2: x0 += k0;  x1 += k1 + 3u;  break;
      case 3: x0 += k1;  x1 += ks2 + 4u; break;
      case 4: x0 += ks2; x1 += k0 + 5u;  break;
    }
  }
  y0 = x0; y1 = x1;
}

__device__ inline bool keep_mask(uint32_t k0, uint32_t k1, uint32_t idx) {
  uint32_t y0, y1;
  tf2x32(k0, k1, 0u, idx, y0, y1);
  return (((y0 ^ y1) >> 31) == 0u);
}

__device__ inline float bf2f(u16 v) {
  union { uint32_t u; float f; } x;
  x.u = ((uint32_t)v) << 16;
  return x.f;
}
__device__ inline u16 f2bf(float f) {
  union { float f; uint32_t u; } x;
  x.f = f;
  uint32_t r = ((x.u >> 16) & 1u) + 0x7FFFu;
  return (u16)((x.u + r) >> 16);
}
__device__ inline float sigm(float x) { return 1.f / (1.f + expf(-x)); }
__device__ inline float ldw(float v) { return v; }
__device__ inline float ldw(u16 v) { return bf2f(v); }

// ---------------- weight f32 -> bf16 conversion (plan A) ----------------
__global__ __launch_bounds__(256) void k_wcvt(const float *__restrict__ s,
                                              u16 *__restrict__ d, int n) {
  int i = (blockIdx.x * 256 + threadIdx.x) * 4;
  int stride = gridDim.x * 256 * 4;
  for (; i < n; i += stride) {
    float4 v = *(const float4 *)(s + i);
    ushort4 o;
    o.x = f2bf(v.x); o.y = f2bf(v.y); o.z = f2bf(v.z); o.w = f2bf(v.w);
    *(ushort4 *)(d + i) = o;
  }
}

// ---------------- prenet layer 1: x1(bf16) = mask1(relu(di @ W1)) * 2 ----------------
__global__ __launch_bounds__(256) void k_prenet1(const float *__restrict__ dec_in,
                                                 const float *__restrict__ W1,
                                                 u16 *__restrict__ x1,
                                                 uint32_t k0, uint32_t k1) {
  int bid = blockIdx.x;
  int t = bid >> 4, b = bid & 15;
  int tid = threadIdx.x;
  __shared__ float di[NMELS];
  if (tid < NMELS)
    di[tid] = (t == 0) ? 0.f : dec_in[((size_t)b * NMELS + tid) * TDEC + (t - 1)];
  __syncthreads();
  int j = tid;
  float acc = 0.f;
#pragma unroll 4
  for (int m = 0; m < NMELS; ++m) acc += di[m] * W1[(size_t)m * PREN + j];
  acc = fmaxf(acc, 0.f);
  uint32_t idx = ((uint32_t)(t * BB + b)) * PREN + (uint32_t)j;
  acc = keep_mask(k0, k1, idx) ? acc * 2.f : 0.f;
  x1[(t * BB + b) * PREN + j] = f2bf(acc);
}

// ---------------- prenet layer 2 -> preT (f32, [t][j][b]) ----------------
__global__ __launch_bounds__(256) void k_prenet2(const u16 *__restrict__ x1,
                                                 const float *__restrict__ W2,
                                                 float *__restrict__ preT,
                                                 uint32_t k0, uint32_t k1) {
  int bid = blockIdx.x;
  int t = bid >> 4, b = bid & 15;
  int tid = threadIdx.x;
  __shared__ float xl[PREN];
  xl[tid] = bf2f(x1[(t * BB + b) * PREN + tid]);
  __syncthreads();
  int j = tid;
  float acc = 0.f;
#pragma unroll 4
  for (int k = 0; k < PREN; ++k) acc += xl[k] * W2[(size_t)k * PREN + j];
  acc = fmaxf(acc, 0.f);
  uint32_t idx = ((uint32_t)(t * BB + b)) * PREN + (uint32_t)j;
  acc = keep_mask(k0, k1, idx) ? acc * 2.f : 0.f;
  preT[(t * PREN + j) * BB + b] = acc;
}

// ---------------- pm = memory @ Wmem (stored bf16) ----------------
__global__ __launch_bounds__(128) void k_pm(const float *__restrict__ memory,
                                            const float *__restrict__ Wmem,
                                            u16 *__restrict__ pm) {
  int bid = blockIdx.x;  // b*TENC + tt
  int tid = threadIdx.x;
  __shared__ float ml[EDIM];
  ((float4 *)ml)[tid] = ((const float4 *)(memory + (size_t)bid * EDIM))[tid];
  __syncthreads();
  int j = tid;
  float acc = 0.f;
#pragma unroll 4
  for (int e = 0; e < EDIM; ++e) acc += ml[e] * Wmem[(size_t)e * ATTN + j];
  pm[(size_t)bid * ATTN + j] = f2bf(acc);
}

// ---------------- split-K LSTM pre-activation GEMM ----------------
// thread = one col; x read via wave-uniform (scalar-cache) loads; weights T = f32 or bf16
template <typename WT, int BK>
__global__ __launch_bounds__(256) void k_zgemm(const WT *__restrict__ Wih,
                                               const WT *__restrict__ Whh,
                                               const float *__restrict__ segA, int lenA,
                                               const float *__restrict__ segB, int lenB,
                                               const float *__restrict__ segC,
                                               float *__restrict__ zp) {
  int tid = threadIdx.x;
  int col = blockIdx.x * 256 + tid;
  int kc = blockIdx.y;
  int kbase = kc * BK;
  int lenAB = lenA + lenB;
  const float *xT; const WT *W; int wrow;
  if (kbase < lenA)       { xT = segA + (size_t)kbase * BB;           W = Wih; wrow = kbase; }
  else if (kbase < lenAB) { xT = segB + (size_t)(kbase - lenA) * BB;  W = Wih; wrow = kbase; }
  else                    { xT = segC + (size_t)(kbase - lenAB) * BB; W = Whh; wrow = kbase - lenAB; }
  const WT *wp = W + (size_t)wrow * 4096 + col;
  float4 s0 = {0, 0, 0, 0}, s1 = {0, 0, 0, 0}, s2 = {0, 0, 0, 0}, s3 = {0, 0, 0, 0};
#pragma unroll 4
  for (int kk = 0; kk < BK; ++kk) {
    float w = ldw(wp[(size_t)kk * 4096]);
    const float4 *xr = (const float4 *)(xT + kk * 16);  // wave-uniform -> s_load
    float4 a0 = xr[0], a1 = xr[1], a2 = xr[2], a3 = xr[3];
    s0.x += a0.x * w; s0.y += a0.y * w; s0.z += a0.z * w; s0.w += a0.w * w;
    s1.x += a1.x * w; s1.y += a1.y * w; s1.z += a1.z * w; s1.w += a1.w * w;
    s2.x += a2.x * w; s2.y += a2.y * w; s2.z += a2.z * w; s2.w += a2.w * w;
    s3.x += a3.x * w; s3.y += a3.y * w; s3.z += a3.z * w; s3.w += a3.w * w;
  }
  float *zo = zp + ((size_t)kc * BB) * 4096 + col;
  zo[0 * 4096] = s0.x; zo[1 * 4096] = s0.y; zo[2 * 4096] = s0.z; zo[3 * 4096] = s0.w;
  zo[4 * 4096] = s1.x; zo[5 * 4096] = s1.y; zo[6 * 4096] = s1.z; zo[7 * 4096] = s1.w;
  zo[8 * 4096] = s2.x; zo[9 * 4096] = s2.y; zo[10 * 4096] = s2.z; zo[11 * 4096] = s2.w;
  zo[12 * 4096] = s3.x; zo[13 * 4096] = s3.y; zo[14 * 4096] = s3.z; zo[15 * 4096] = s3.w;
}

// ---------------- fused aLSTM-activation + attention (one block per batch row) ----------------
__global__ __launch_bounds__(1024) void k_att(const float *__restrict__ z1p, int nch,
                                              const float *__restrict__ ab,
                                              float *__restrict__ ac,
                                              float *__restrict__ ahT,
                                              float *__restrict__ aw, float *__restrict__ awc,
                                              const u16 *__restrict__ pm,
                                              const float *__restrict__ Wq,
                                              const float *__restrict__ vw,
                                              const float *__restrict__ convW,
                                              const float *__restrict__ ldW,
                                              const float *__restrict__ memory,
                                              const int *__restrict__ mlen,
                                              float *__restrict__ ctx, float *__restrict__ ctxT,
                                              float *__restrict__ align_out, int t) {
  int b = blockIdx.x;
  int tid = threadIdx.x;
  __shared__ float ah_l[ARN];
  __shared__ float aw_l[288], awc_l[288];
  __shared__ float lc[TENC * 33];
  __shared__ float pqp[ATTN * 8];
  __shared__ float pq[ATTN];
  __shared__ float ep[TENC * 4];
  __shared__ float e_l[TENC];
  __shared__ float cp[2][EDIM];
  __shared__ float red[32];
  __shared__ float s_max, s_inv;

  // ---- phase A: reduce z1 partials -> ah ----
  {
    int u = tid;
    float zi = 0.f, zf = 0.f, zg = 0.f, zo = 0.f;
    for (int kc = 0; kc < nch; ++kc) {
      const float *z = z1p + ((size_t)kc * BB + b) * 4096;
      zi += z[u]; zf += z[u + 1024]; zg += z[u + 2048]; zo += z[u + 3072];
    }
    zi += ab[u]; zf += ab[u + 1024]; zg += ab[u + 2048]; zo += ab[u + 3072];
    float cn = sigm(zf) * ac[b * 1024 + u] + sigm(zi) * tanhf(zg);
    float hn = sigm(zo) * tanhf(cn);
    ac[b * 1024 + u] = cn;
    ahT[u * BB + b] = hn;
    ah_l[u] = hn;
  }
  if (tid < TENC) { aw_l[16 + tid] = aw[b * TENC + tid]; awc_l[16 + tid] = awc[b * TENC + tid]; }
  if (tid < 16) { aw_l[tid] = 0.f; aw_l[272 + tid] = 0.f; awc_l[tid] = 0.f; awc_l[272 + tid] = 0.f; }
  __syncthreads();

  // ---- pq = ah @ Wq ----
  {
    int j = tid & 127, kc = tid >> 7;
    float a = 0.f;
    const float *wq = Wq + (size_t)(kc * 128) * ATTN + j;
#pragma unroll 4
    for (int kk = 0; kk < 128; ++kk) a += ah_l[kc * 128 + kk] * wq[(size_t)kk * ATTN];
    pqp[j * 8 + kc] = a;
  }
  __syncthreads();
  if (tid < ATTN) {
    float s = 0.f;
#pragma unroll
    for (int kc = 0; kc < 8; ++kc) s += pqp[tid * 8 + kc];
    pq[tid] = s;
  }
  // ---- location conv ----
  {
    int tt = tid & 255, fg = tid >> 8;
    float acc8[8] = {0, 0, 0, 0, 0, 0, 0, 0};
    for (int k = 0; k < KSIZE; ++k) {
      float a = aw_l[tt + k + 1];
      float cc = awc_l[tt + k + 1];
#pragma unroll
      for (int f8 = 0; f8 < 8; ++f8) {
        int f = fg * 8 + f8;
        acc8[f8] += a * convW[(size_t)f * 62 + k] + cc * convW[(size_t)f * 62 + 31 + k];
      }
    }
#pragma unroll
    for (int f8 = 0; f8 < 8; ++f8) lc[tt * 33 + fg * 8 + f8] = acc8[f8];
  }
  __syncthreads();
  // ---- energies ----
  {
    int tt = tid & 255, jg = tid >> 8;
    float esum = 0.f;
    const u16 *pmrow = pm + ((size_t)(b * TENC + tt)) * ATTN;
    for (int jj = 0; jj < 32; ++jj) {
      int j = jg * 32 + jj;
      float s = pq[j] + bf2f(pmrow[j]);
#pragma unroll
      for (int f = 0; f < NFILT; ++f) s += lc[tt * 33 + f] * ldW[(size_t)f * ATTN + j];
      esum += tanhf(s) * vw[j];
    }
    ep[tt * 4 + jg] = esum;
  }
  __syncthreads();
  int len = mlen[b];
  if (tid < TENC) {
    float e = ep[tid * 4] + ep[tid * 4 + 1] + ep[tid * 4 + 2] + ep[tid * 4 + 3];
    if (tid >= len) e = -1e9f;
    e_l[tid] = e;
  }
  __syncthreads();
  if (tid < 32) {
    float m = -1e30f;
#pragma unroll
    for (int i = 0; i < 8; ++i) m = fmaxf(m, e_l[tid * 8 + i]);
    red[tid] = m;
  }
  __syncthreads();
  if (tid == 0) {
    float m = -1e30f;
    for (int i = 0; i < 32; ++i) m = fmaxf(m, red[i]);
    s_max = m;
  }
  __syncthreads();
  if (tid < TENC) e_l[tid] = expf(e_l[tid] - s_max);
  __syncthreads();
  if (tid < 32) {
    float s = 0.f;
#pragma unroll
    for (int i = 0; i < 8; ++i) s += e_l[tid * 8 + i];
    red[tid] = s;
  }
  __syncthreads();
  if (tid == 0) {
    float s = 0.f;
    for (int i = 0; i < 32; ++i) s += red[i];
    s_inv = 1.f / s;
  }
  __syncthreads();
  if (tid < TENC) {
    float w = e_l[tid] * s_inv;
    e_l[tid] = w;
    aw[b * TENC + tid] = w;
    awc[b * TENC + tid] = awc_l[16 + tid] + w;
    align_out[((size_t)b * TDEC + t) * TENC + tid] = w;
  }
  __syncthreads();
  // ---- ctx = w @ memory ----
  {
    int e = tid & 511, h = tid >> 9;
    int t0 = h * 128, t1 = min(len, (h + 1) * 128);
    float a = 0.f;
    for (int tt = t0; tt < t1; ++tt)
      a += e_l[tt] * memory[((size_t)b * TENC + tt) * EDIM + e];
    cp[h][e] = a;
  }
  __syncthreads();
  if (tid < EDIM) {
    float v = cp[0][tid] + cp[1][tid];
    ctx[b * EDIM + tid] = v;
    ctxT[tid * BB + b] = v;
  }
}

// ---------------- fused dLSTM-activation + projection ----------------
__global__ __launch_bounds__(256) void k_out(const float *__restrict__ z2p, int nch,
                                             const float *__restrict__ db,
                                             float *__restrict__ dc,
                                             float *__restrict__ dhT,
                                             const float *__restrict__ ctx,
                                             const float *__restrict__ projW,
                                             const float *__restrict__ projB,
                                             const float *__restrict__ gateW,
                                             const float *__restrict__ gateB,
                                             float *__restrict__ mel_out,
                                             float *__restrict__ gate_out, int t) {
  int b = blockIdx.x;
  int tid = threadIdx.x;
  __shared__ float xl[1536];
  __shared__ float part[3 * 81];
#pragma unroll
  for (int r = 0; r < 4; ++r) {
    int u = r * 256 + tid;
    float zi = 0.f, zf = 0.f, zg = 0.f, zo = 0.f;
    for (int kc = 0; kc < nch; ++kc) {
      const float *z = z2p + ((size_t)kc * BB + b) * 4096;
      zi += z[u]; zf += z[u + 1024]; zg += z[u + 2048]; zo += z[u + 3072];
    }
    zi += db[u]; zf += db[u + 1024]; zg += db[u + 2048]; zo += db[u + 3072];
    float cn = sigm(zf) * dc[b * 1024 + u] + sigm(zi) * tanhf(zg);
    float hn = sigm(zo) * tanhf(cn);
    dc[b * 1024 + u] = cn;
    dhT[u * BB + b] = hn;
    xl[u] = hn;
  }
  for (int i = tid; i < EDIM; i += 256) xl[1024 + i] = ctx[b * EDIM + i];
  __syncthreads();
  if (tid < 243) {
    int col = tid % 81;
    int kc = tid / 81;
    float a = 0.f;
#pragma unroll 4
    for (int kk = 0; kk < 512; ++kk) {
      int k = kc * 512 + kk;
      float wv = (col < 80) ? projW[(size_t)k * NMELS + col] : gateW[k];
      a += xl[k] * wv;
    }
    part[kc * 81 + col] = a;
  }
  __syncthreads();
  if (tid < 81) {
    float s = part[tid] + part[81 + tid] + part[162 + tid];
    if (tid < 80) {
      s += projB[tid];
      mel_out[((size_t)b * NMELS + tid) * TDEC + t] = s;
    } else {
      s += gateB[0];
      gate_out[(size_t)b * TDEC + t] = s;
    }
  }
}

extern "C" void kernel_launch(void *const *d_in, const int *in_sizes, int n_in,
                              void *d_out, int out_size, void *d_ws, size_t ws_size,
                              hipStream_t stream) {
  (void)in_sizes; (void)n_in; (void)out_size;
  const float *memory = (const float *)d_in[0];
  const float *dec_in = (const float *)d_in[1];
  const int   *mlen   = (const int *)d_in[2];
  const float *pw1    = (const float *)d_in[3];
  const float *pw2    = (const float *)d_in[4];
  const float *aWih   = (const float *)d_in[5];
  const float *aWhh   = (const float *)d_in[6];
  const float *ab     = (const float *)d_in[7];
  const float *wq     = (const float *)d_in[8];
  const float *wmem   = (const float *)d_in[9];
  const float *vw     = (const float *)d_in[10];
  const float *convW  = (const float *)d_in[11];
  const float *ldW    = (const float *)d_in[12];
  const float *dWih   = (const float *)d_in[13];
  const float *dWhh   = (const float *)d_in[14];
  const float *db     = (const float *)d_in[15];
  const float *projW  = (const float *)d_in[16];
  const float *projB  = (const float *)d_in[17];
  const float *gateW  = (const float *)d_in[18];
  const float *gateB  = (const float *)d_in[19];

  float *out_mel  = (float *)d_out;
  float *out_gate = out_mel + (size_t)16 * 80 * 200;
  float *out_algn = out_gate + (size_t)16 * 200;

  // ---- ws_size-based plan cascade ----
  // plan A: bf16 weights + BK=128     -> 11,395,072 floats (45.6 MB)
  // plan B: f32 weights  + BK=128     ->  2,482,176 floats ( 9.9 MB)
  // plan C: f32 weights  + BK=256     ->  1,826,816 floats ( 7.3 MB, proven)
  int plan = (ws_size >= 11395072ull * 4) ? 0 : (ws_size >= 2482176ull * 4) ? 1 : 2;
  size_t zsize = (plan == 2) ? 655360 : 1310720;
  int nch1 = (plan == 2) ? 7 : 14;   // K=1792
  int nch2 = (plan == 2) ? 10 : 20;  // K=2560

  float *ws = (float *)d_ws;
  float *st   = ws;                        // 90112 state floats
  float *preT = ws + 90112;                // 819200
  u16   *pmu  = (u16 *)(ws + 909312);      // 262144 floats worth
  float *z    = ws + 1171456;              // zsize
  u16   *x1u  = (u16 *)z;                  // pre-loop alias (409600 f < zsize)
  u16   *wb   = (u16 *)(ws + 1171456 + zsize);  // plan A only
  u16 *aWihB = wb;
  u16 *aWhhB = wb + 3145728;
  u16 *dWihB = wb + 7340032;
  u16 *dWhhB = wb + 13631488;

  float *ahT  = st;
  float *ac   = ahT + 16384;
  float *dhT  = ac + 16384;
  float *dc   = dhT + 16384;
  float *ctx  = dc + 16384;
  float *ctxT = ctx + 8192;
  float *aw   = ctxT + 8192;
  float *awc  = aw + 4096;

  hipMemsetAsync(st, 0, 90112 * sizeof(float), stream);

  uint32_t K1a, K1b, K2a, K2b;
  tf2x32(0u, 42u, 0u, 0u, K1a, K1b);
  tf2x32(0u, 42u, 0u, 1u, K2a, K2b);

  if (plan == 0) {
    k_wcvt<<<512, 256, 0, stream>>>(aWih, aWihB, 3145728);
    k_wcvt<<<512, 256, 0, stream>>>(aWhh, aWhhB, 4194304);
    k_wcvt<<<512, 256, 0, stream>>>(dWih, dWihB, 6291456);
    k_wcvt<<<512, 256, 0, stream>>>(dWhh, dWhhB, 4194304);
  }

  k_prenet1<<<TDEC * BB, 256, 0, stream>>>(dec_in, pw1, x1u, K1a, K1b);
  k_prenet2<<<TDEC * BB, 256, 0, stream>>>(x1u, pw2, preT, K2a, K2b);
  k_pm<<<BB * TENC, 128, 0, stream>>>(memory, wmem, pmu);

  for (int t = 0; t < TDEC; ++t) {
    const float *preTt = preT + (size_t)t * PREN * BB;
    if (plan == 0)
      k_zgemm<u16, 128><<<dim3(16, nch1), 256, 0, stream>>>(aWihB, aWhhB, preTt, PREN,
                                                            ctxT, EDIM, ahT, z);
    else if (plan == 1)
      k_zgemm<float, 128><<<dim3(16, nch1), 256, 0, stream>>>(aWih, aWhh, preTt, PREN,
                                                              ctxT, EDIM, ahT, z);
    else
      k_zgemm<float, 256><<<dim3(16, nch1), 256, 0, stream>>>(aWih, aWhh, preTt, PREN,
                                                              ctxT, EDIM, ahT, z);
    k_att<<<16, 1024, 0, stream>>>(z, nch1, ab, ac, ahT, aw, awc, pmu, wq, vw, convW, ldW,
                                   memory, mlen, ctx, ctxT, out_algn, t);
    if (plan == 0)
      k_zgemm<u16, 128><<<dim3(16, nch2), 256, 0, stream>>>(dWihB, dWhhB, ahT, ARN,
                                                            ctxT, EDIM, dhT, z);
    else if (plan == 1)
      k_zgemm<float, 128><<<dim3(16, nch2), 256, 0, stream>>>(dWih, dWhh, ahT, ARN,
                                                              ctxT, EDIM, dhT, z);
    else
      k_zgemm<float, 256><<<dim3(16, nch2), 256, 0, stream>>>(dWih, dWhh, ahT, ARN,
                                                              ctxT, EDIM, dhT, z);
    k_out<<<16, 256, 0, stream>>>(z, nch2, db, dc, dhT, ctx, projW, projB, gateW, gateB,
                                  out_mel, out_gate, t);
  }
}